// Round 8
// baseline (766.096 us; speedup 1.0000x reference)
//
#include <hip/hip_runtime.h>
#include <hip/hip_bf16.h>
#include <hip/hip_cooperative_groups.h>

namespace cg = cooperative_groups;

typedef _Float16 f16x2 __attribute__((ext_vector_type(2)));
typedef _Float16 f16x4 __attribute__((ext_vector_type(4)));
typedef _Float16 f16x8 __attribute__((ext_vector_type(8)));
typedef float    f32x4 __attribute__((ext_vector_type(4)));
typedef float    f32x16 __attribute__((ext_vector_type(16)));

#define IN_DIM   32
#define EDGE_DIM 16
#define HDIM     64
#define OUT_DIM  6
#define BN_EPS   1e-5f

struct FusedParams {
    const float *x, *ea, *We, *be, *Wx, *bx, *Wroot, *broot, *gam, *bet, *rmean, *rvar, *W1, *b1, *W2, *b2;
    const int *src, *dst, *batch;
    float *out;
    float *h0, *h1, *agg;
    _Float16 *eaH;
    uint4 *WeB;
    int *degI, *start;
    int N, E, G;
};

// ================= single cooperative kernel: all phases, zero launch gaps =================
__global__ __launch_bounds__(256, 4) void k_fused(FusedParams p) {
    cg::grid_group grid = cg::this_grid();
    __shared__ __align__(16) float hsT[64][68];   // 17408 B
    __shared__ float beL[4096];                   // 16384 B  (total 33792 B -> 4 blocks/CU)
    const int t  = threadIdx.x;
    const int l  = t & 63;
    const int w  = t >> 6;
    const int b0 = blockIdx.x;
    const int gs = gridDim.x;

    // ---------- Z: zero agg + degI ----------
    {
        int nz = p.N * 16;                         // agg as uint4
        for (int i = b0 * 256 + t; i < nz; i += gs * 256)
            ((uint4*)p.agg)[i] = make_uint4(0u, 0u, 0u, 0u);
        for (int i = b0 * 256 + t; i < p.N; i += gs * 256) p.degI[i] = 0;
    }
    grid.sync();

    // ---------- S: setup = pack WeB | encode h0 | prep eaH+deg | bounds ----------
    {
        const int PACKB = 96;
        const int ENCB  = (p.N * 16 + 255) / 256;
        const int PREPB = (p.E * 8 + 255) / 256;
        const int VB    = PACKB + ENCB + PREPB + 1;
        for (int vb = b0; vb < VB; vb += gs) {
            if (vb < PACKB) {
                // pack: WeB[layer][h*2+oh][lane] f16x8; lane col=oh*32+(lane&31), k=8*(lane>>5)+j
                int tid = vb * 256 + t;
                int tile = tid >> 6, lane = tid & 63;
                int layer = tile >> 7;
                int r = tile & 127;
                int hh = r >> 1, oh = r & 1;
                int col = hh * 64 + oh * 32 + (lane & 31);
                int kbase = 8 * (lane >> 5);
                const float* base = p.We + (size_t)layer * 65536 + col;
                f16x8 v;
                #pragma unroll
                for (int j = 0; j < 8; ++j) v[j] = (_Float16)base[(size_t)(kbase + j) * 4096];
                p.WeB[(size_t)tile * 64 + lane] = __builtin_bit_cast(uint4, v);
            } else if (vb < PACKB + ENCB) {
                int tid = (vb - PACKB) * 256 + t;
                int n = tid >> 4, jq = tid & 15;
                if (n < p.N) {
                    const float4* W4 = (const float4*)p.Wx;
                    float4 acc = ((const float4*)p.bx)[jq];
                    const float4* xv = (const float4*)(p.x + (size_t)n * IN_DIM);
                    #pragma unroll
                    for (int k4 = 0; k4 < 8; ++k4) {
                        float4 xk = xv[k4];
                        #pragma unroll
                        for (int i = 0; i < 4; ++i) {
                            float xs = (i == 0) ? xk.x : (i == 1) ? xk.y : (i == 2) ? xk.z : xk.w;
                            float4 ww = W4[(k4 * 4 + i) * 16 + jq];
                            acc.x += xs * ww.x; acc.y += xs * ww.y;
                            acc.z += xs * ww.z; acc.w += xs * ww.w;
                        }
                    }
                    ((float4*)p.h0)[tid] = acc;
                }
            } else if (vb < PACKB + ENCB + PREPB) {
                int tid = (vb - PACKB - ENCB) * 256 + t;
                int E8 = p.E * 8;
                if (tid < E8) {
                    float2 v = ((const float2*)p.ea)[tid];
                    f16x2 r2; r2[0] = (_Float16)v.x; r2[1] = (_Float16)v.y;
                    ((f16x2*)p.eaH)[tid] = r2;
                }
                if (tid < p.E) atomicAdd(&p.degI[p.dst[tid]], 1);
            } else {
                if (t <= p.G) {
                    int lo = 0, hi = p.N;
                    while (lo < hi) { int mid = (lo + hi) >> 1; if (p.batch[mid] < t) lo = mid + 1; else hi = mid; }
                    p.start[t] = lo;
                }
            }
        }
    }
    grid.sync();

    const int EG  = (p.E + 63) / 64;
    const int NBu = (p.N * 16 + 255) / 256;
    float* ha = p.h0;
    float* hb = p.h1;

    #pragma unroll 1
    for (int layer = 0; layer < 3; ++layer) {
        const float* hin = ha;
        float* hout = hb;
        const uint4* WeL = p.WeB + (size_t)layer * 8192;
        const float* beG = p.be + (size_t)layer * 4096;

        // stage this layer's biases once per block
        {
            const float4* bg = (const float4*)beG;
            float4* bs = (float4*)beL;
            for (int i = t; i < 1024; i += 256) bs[i] = bg[i];
        }
        __syncthreads();

        // ---------- E: edge MLP (32x32x16 MFMA, K=16) + relu*hs reduce + atomic scatter ----------
        const int gp = w >> 1;                // edge half (32 edges)
        const int oh = w & 1;                 // o half (32 outs)
        const int row = l & 31;
        const int kg  = l >> 5;               // k-group (8 of 16 k)
        const int obase = oh * 32;
        for (int eg = b0; eg < EG; eg += gs) {
            const int eb = eg * 64;
            // stage hsT: wave w stages h-rows w*16..w*16+15 for all 64 edges
            {
                int egc = min(eb + l, p.E - 1);
                int s = p.src[egc];
                const float4* hp = (const float4*)(hin + (size_t)s * HDIM + w * 16);
                float4 a = hp[0], b = hp[1], c = hp[2], d = hp[3];
                hsT[w*16+ 0][l] = a.x; hsT[w*16+ 1][l] = a.y; hsT[w*16+ 2][l] = a.z; hsT[w*16+ 3][l] = a.w;
                hsT[w*16+ 4][l] = b.x; hsT[w*16+ 5][l] = b.y; hsT[w*16+ 6][l] = b.z; hsT[w*16+ 7][l] = b.w;
                hsT[w*16+ 8][l] = c.x; hsT[w*16+ 9][l] = c.y; hsT[w*16+10][l] = c.z; hsT[w*16+11][l] = c.w;
                hsT[w*16+12][l] = d.x; hsT[w*16+13][l] = d.y; hsT[w*16+14][l] = d.z; hsT[w*16+15][l] = d.w;
            }
            __syncthreads();

            const int ebw = eb + gp * 32;
            const int elw = gp * 32;
            int ea_e = min(ebw + row, p.E - 1);
            f16x8 A = __builtin_bit_cast(f16x8, ((const uint4*)p.eaH)[(size_t)ea_e * 2 + kg]);

            float m[16];
            #pragma unroll
            for (int j = 0; j < 16; ++j) m[j] = 0.f;

            const uint4* Bb = WeL + (size_t)oh * 64 + l;
            uint4 Bv = Bb[0];
            for (int hh = 0; hh < 64; ++hh) {
                uint4 Bn;
                if (hh < 63) Bn = Bb[(size_t)(hh + 1) * 128];
                float bias = beL[hh * 64 + obase + row];
                f32x16 cin;
                #pragma unroll
                for (int j = 0; j < 16; ++j) cin[j] = bias;
                f32x16 z = __builtin_amdgcn_mfma_f32_32x32x16_f16(
                    A, __builtin_bit_cast(f16x8, Bv), cin, 0, 0, 0);
                float4 q0 = *(const float4*)&hsT[hh][elw + 4 * kg + 0];
                float4 q1 = *(const float4*)&hsT[hh][elw + 4 * kg + 8];
                float4 q2 = *(const float4*)&hsT[hh][elw + 4 * kg + 16];
                float4 q3 = *(const float4*)&hsT[hh][elw + 4 * kg + 24];
                m[0]  += fmaxf(z[0],  0.f) * q0.x;
                m[1]  += fmaxf(z[1],  0.f) * q0.y;
                m[2]  += fmaxf(z[2],  0.f) * q0.z;
                m[3]  += fmaxf(z[3],  0.f) * q0.w;
                m[4]  += fmaxf(z[4],  0.f) * q1.x;
                m[5]  += fmaxf(z[5],  0.f) * q1.y;
                m[6]  += fmaxf(z[6],  0.f) * q1.z;
                m[7]  += fmaxf(z[7],  0.f) * q1.w;
                m[8]  += fmaxf(z[8],  0.f) * q2.x;
                m[9]  += fmaxf(z[9],  0.f) * q2.y;
                m[10] += fmaxf(z[10], 0.f) * q2.z;
                m[11] += fmaxf(z[11], 0.f) * q2.w;
                m[12] += fmaxf(z[12], 0.f) * q3.x;
                m[13] += fmaxf(z[13], 0.f) * q3.y;
                m[14] += fmaxf(z[14], 0.f) * q3.z;
                m[15] += fmaxf(z[15], 0.f) * q3.w;
                Bv = Bn;
            }
            // scatter: one f32 atomic per (e,o); 32-lane coalesced segments
            #pragma unroll
            for (int j = 0; j < 16; ++j) {
                int e = ebw + (j & 3) + 8 * (j >> 2) + 4 * kg;
                if (e < p.E) {
                    int d = p.dst[e];
                    atomicAdd(&p.agg[(size_t)d * HDIM + obase + row], m[j]);
                }
            }
            __syncthreads();   // protect hsT before next item restage
        }
        grid.sync();

        // ---------- U: node update (coalesced agg read + self-zero) ----------
        for (int vb = b0; vb < NBu; vb += gs) {
            int tid = vb * 256 + t;
            int n = tid >> 4, jq = tid & 15;
            if (n < p.N) {
                float dinv = 1.0f / fmaxf((float)p.degI[n], 1.0f);
                float4 acc = ((const float4*)(p.broot + (size_t)layer * 64))[jq];
                float4 ag = ((const float4*)p.agg)[tid];
                ((float4*)p.agg)[tid] = make_float4(0.f, 0.f, 0.f, 0.f);  // clean for next layer
                acc.x += ag.x * dinv; acc.y += ag.y * dinv;
                acc.z += ag.z * dinv; acc.w += ag.w * dinv;
                const float4* W4 = (const float4*)(p.Wroot + (size_t)layer * 4096);
                const float4* hv = (const float4*)(hin + (size_t)n * HDIM);
                #pragma unroll
                for (int k4 = 0; k4 < 16; ++k4) {
                    float4 hk = hv[k4];
                    #pragma unroll
                    for (int i = 0; i < 4; ++i) {
                        float hsc = (i == 0) ? hk.x : (i == 1) ? hk.y : (i == 2) ? hk.z : hk.w;
                        float4 ww = W4[(k4 * 4 + i) * 16 + jq];
                        acc.x += hsc * ww.x; acc.y += hsc * ww.y;
                        acc.z += hsc * ww.z; acc.w += hsc * ww.w;
                    }
                }
                acc.x = fmaxf(acc.x, 0.f); acc.y = fmaxf(acc.y, 0.f);
                acc.z = fmaxf(acc.z, 0.f); acc.w = fmaxf(acc.w, 0.f);
                float4 g4 = ((const float4*)(p.gam + (size_t)layer * 64))[jq];
                float4 b4 = ((const float4*)(p.bet + (size_t)layer * 64))[jq];
                float4 mm4 = ((const float4*)(p.rmean + (size_t)layer * 64))[jq];
                float4 v4 = ((const float4*)(p.rvar + (size_t)layer * 64))[jq];
                float4 hres = ((const float4*)hin)[tid];
                float4 y;
                y.x = g4.x * (acc.x - mm4.x) * rsqrtf(v4.x + BN_EPS) + b4.x + hres.x;
                y.y = g4.y * (acc.y - mm4.y) * rsqrtf(v4.y + BN_EPS) + b4.y + hres.y;
                y.z = g4.z * (acc.z - mm4.z) * rsqrtf(v4.z + BN_EPS) + b4.z + hres.z;
                y.w = g4.w * (acc.w - mm4.w) * rsqrtf(v4.w + BN_EPS) + b4.w + hres.w;
                ((float4*)hout)[tid] = y;
            }
        }
        grid.sync();
        float* tmp = hb; hb = ha; ha = tmp;    // ha now holds latest h
    }

    // ---------- P: pool (segment mean) + MLP head ----------
    {
        const float* hf = ha;                  // after 3 swaps: final h
        float* sums = &hsT[0][0];              // reuse LDS: [16][68]
        float* pl = beL;                       // [64]
        float* zl = beL + 64;                  // [64]
        int jq = t & 15, rp = t >> 4;
        for (int g = b0; g < p.G; g += gs) {
            int s0 = p.start[g], s1 = p.start[g + 1];
            float4 acc = make_float4(0.f, 0.f, 0.f, 0.f);
            for (int n = s0 + rp; n < s1; n += 16) {
                float4 v = ((const float4*)hf)[(size_t)n * 16 + jq];
                acc.x += v.x; acc.y += v.y; acc.z += v.z; acc.w += v.w;
            }
            *(float4*)&sums[rp * 68 + jq * 4] = acc;
            __syncthreads();
            if (t < HDIM) {
                float a = 0.f;
                #pragma unroll
                for (int r = 0; r < 16; ++r) a += sums[r * 68 + t];
                pl[t] = a / fmaxf((float)(s1 - s0), 1.0f);
            }
            __syncthreads();
            if (t < HDIM) {
                float a = p.b1[t];
                #pragma unroll
                for (int k = 0; k < HDIM; ++k) a += pl[k] * p.W1[k * HDIM + t];
                zl[t] = fmaxf(a, 0.f);
            }
            __syncthreads();
            if (t < OUT_DIM) {
                float a = p.b2[t];
                #pragma unroll
                for (int k = 0; k < HDIM; ++k) a += zl[k] * p.W2[k * OUT_DIM + t];
                p.out[(size_t)g * OUT_DIM + t] = a;
            }
            __syncthreads();
        }
    }
}

// ======================= fallback (non-cooperative) path: R7 kernels =======================
__global__ void k_zero(uint4* __restrict__ p, int n16) {
    int i = blockIdx.x * 256 + threadIdx.x;
    if (i < n16) p[i] = make_uint4(0u, 0u, 0u, 0u);
}

__global__ __launch_bounds__(256) void k_setup(
    const float* __restrict__ We, uint4* __restrict__ WeB,
    const float* __restrict__ x, const float* __restrict__ Wx,
    const float* __restrict__ bx, float* __restrict__ h,
    const float* __restrict__ ea, _Float16* __restrict__ eaH,
    const int* __restrict__ dstI, int* __restrict__ degI,
    const int* __restrict__ batch, int* __restrict__ start,
    int N, int E, int G, int PACKB, int ENCB, int PREPB)
{
    int bid = blockIdx.x;
    int t = threadIdx.x;
    if (bid < PACKB) {
        int tid = bid * 256 + t;
        int tile = tid >> 6, lane = tid & 63;
        int layer = tile >> 7;
        int r = tile & 127;
        int hh = r >> 1, oh = r & 1;
        int col = hh * 64 + oh * 32 + (lane & 31);
        int kbase = 8 * (lane >> 5);
        const float* base = We + (size_t)layer * 65536 + col;
        f16x8 v;
        #pragma unroll
        for (int j = 0; j < 8; ++j) v[j] = (_Float16)base[(size_t)(kbase + j) * 4096];
        WeB[(size_t)tile * 64 + lane] = __builtin_bit_cast(uint4, v);
        return;
    }
    bid -= PACKB;
    if (bid < ENCB) {
        int tid = bid * 256 + t;
        int n = tid >> 4, jq = tid & 15;
        if (n >= N) return;
        const float4* W4 = (const float4*)Wx;
        float4 acc = ((const float4*)bx)[jq];
        const float4* xv = (const float4*)(x + (size_t)n * IN_DIM);
        #pragma unroll
        for (int k4 = 0; k4 < 8; ++k4) {
            float4 xk = xv[k4];
            #pragma unroll
            for (int i = 0; i < 4; ++i) {
                float xs = (i == 0) ? xk.x : (i == 1) ? xk.y : (i == 2) ? xk.z : xk.w;
                float4 ww = W4[(k4 * 4 + i) * 16 + jq];
                acc.x += xs * ww.x; acc.y += xs * ww.y; acc.z += xs * ww.z; acc.w += xs * ww.w;
            }
        }
        ((float4*)h)[tid] = acc;
        return;
    }
    bid -= ENCB;
    if (bid < PREPB) {
        int tid = bid * 256 + t;
        int E8 = E * 8;
        if (tid < E8) {
            float2 v = ((const float2*)ea)[tid];
            f16x2 r; r[0] = (_Float16)v.x; r[1] = (_Float16)v.y;
            ((f16x2*)eaH)[tid] = r;
        }
        if (tid < E) atomicAdd(&degI[dstI[tid]], 1);
        return;
    }
    if (t <= G) {
        int lo = 0, hi = N;
        while (lo < hi) { int mid = (lo + hi) >> 1; if (batch[mid] < t) lo = mid + 1; else hi = mid; }
        start[t] = lo;
    }
}

__global__ __launch_bounds__(256, 4) void k_edge_fb(
    const uint4* __restrict__ eaH4, const uint4* __restrict__ WeB,
    const float* __restrict__ be, const float* __restrict__ hin,
    const int* __restrict__ srcI, const int* __restrict__ dstI,
    float* __restrict__ agg, int E)
{
    __shared__ __align__(16) float hsT[64][68];
    __shared__ float beL[4096];
    const int t = threadIdx.x;
    const int l = t & 63;
    const int w = t >> 6;
    const int eb = blockIdx.x * 64;
    {
        const float4* bg = (const float4*)be;
        float4* bs = (float4*)beL;
        for (int i = t; i < 1024; i += 256) bs[i] = bg[i];
    }
    {
        int egc = min(eb + l, E - 1);
        int s = srcI[egc];
        const float4* hp = (const float4*)(hin + (size_t)s * HDIM + w * 16);
        float4 a = hp[0], b = hp[1], c = hp[2], d = hp[3];
        hsT[w*16+ 0][l] = a.x; hsT[w*16+ 1][l] = a.y; hsT[w*16+ 2][l] = a.z; hsT[w*16+ 3][l] = a.w;
        hsT[w*16+ 4][l] = b.x; hsT[w*16+ 5][l] = b.y; hsT[w*16+ 6][l] = b.z; hsT[w*16+ 7][l] = b.w;
        hsT[w*16+ 8][l] = c.x; hsT[w*16+ 9][l] = c.y; hsT[w*16+10][l] = c.z; hsT[w*16+11][l] = c.w;
        hsT[w*16+12][l] = d.x; hsT[w*16+13][l] = d.y; hsT[w*16+14][l] = d.z; hsT[w*16+15][l] = d.w;
    }
    __syncthreads();
    const int gp = w >> 1, oh = w & 1;
    const int ebw = eb + gp * 32, elw = gp * 32;
    const int row = l & 31, kg = l >> 5, obase = oh * 32;
    int ea_e = min(ebw + row, E - 1);
    f16x8 A = __builtin_bit_cast(f16x8, eaH4[(size_t)ea_e * 2 + kg]);
    float m[16];
    #pragma unroll
    for (int j = 0; j < 16; ++j) m[j] = 0.f;
    const uint4* Bb = WeB + (size_t)oh * 64 + l;
    uint4 Bv = Bb[0];
    for (int hh = 0; hh < 64; ++hh) {
        uint4 Bn;
        if (hh < 63) Bn = Bb[(size_t)(hh + 1) * 128];
        float bias = beL[hh * 64 + obase + row];
        f32x16 cin;
        #pragma unroll
        for (int j = 0; j < 16; ++j) cin[j] = bias;
        f32x16 z = __builtin_amdgcn_mfma_f32_32x32x16_f16(A, __builtin_bit_cast(f16x8, Bv), cin, 0, 0, 0);
        float4 q0 = *(const float4*)&hsT[hh][elw + 4 * kg + 0];
        float4 q1 = *(const float4*)&hsT[hh][elw + 4 * kg + 8];
        float4 q2 = *(const float4*)&hsT[hh][elw + 4 * kg + 16];
        float4 q3 = *(const float4*)&hsT[hh][elw + 4 * kg + 24];
        m[0]+=fmaxf(z[0],0.f)*q0.x;  m[1]+=fmaxf(z[1],0.f)*q0.y;
        m[2]+=fmaxf(z[2],0.f)*q0.z;  m[3]+=fmaxf(z[3],0.f)*q0.w;
        m[4]+=fmaxf(z[4],0.f)*q1.x;  m[5]+=fmaxf(z[5],0.f)*q1.y;
        m[6]+=fmaxf(z[6],0.f)*q1.z;  m[7]+=fmaxf(z[7],0.f)*q1.w;
        m[8]+=fmaxf(z[8],0.f)*q2.x;  m[9]+=fmaxf(z[9],0.f)*q2.y;
        m[10]+=fmaxf(z[10],0.f)*q2.z; m[11]+=fmaxf(z[11],0.f)*q2.w;
        m[12]+=fmaxf(z[12],0.f)*q3.x; m[13]+=fmaxf(z[13],0.f)*q3.y;
        m[14]+=fmaxf(z[14],0.f)*q3.z; m[15]+=fmaxf(z[15],0.f)*q3.w;
        Bv = Bn;
    }
    #pragma unroll
    for (int j = 0; j < 16; ++j) {
        int e = ebw + (j & 3) + 8 * (j >> 2) + 4 * kg;
        if (e < E) atomicAdd(&agg[(size_t)dstI[e] * HDIM + obase + row], m[j]);
    }
}

__global__ void k_update_fb(
    float* __restrict__ agg, const int* __restrict__ degI,
    const float* __restrict__ hin, const float* __restrict__ Wroot,
    const float* __restrict__ broot, const float* __restrict__ gam,
    const float* __restrict__ bet, const float* __restrict__ rmean,
    const float* __restrict__ rvar, float* __restrict__ hout, int N)
{
    int tid = blockIdx.x * 256 + threadIdx.x;
    int n = tid >> 4, jq = tid & 15;
    if (n >= N) return;
    float dinv = 1.0f / fmaxf((float)degI[n], 1.0f);
    float4 acc = ((const float4*)broot)[jq];
    float4 ag = ((const float4*)agg)[tid];
    ((float4*)agg)[tid] = make_float4(0.f, 0.f, 0.f, 0.f);
    acc.x += ag.x * dinv; acc.y += ag.y * dinv; acc.z += ag.z * dinv; acc.w += ag.w * dinv;
    const float4* W4 = (const float4*)Wroot;
    const float4* hv = (const float4*)(hin + (size_t)n * HDIM);
    #pragma unroll
    for (int k4 = 0; k4 < 16; ++k4) {
        float4 hk = hv[k4];
        #pragma unroll
        for (int i = 0; i < 4; ++i) {
            float hsc = (i == 0) ? hk.x : (i == 1) ? hk.y : (i == 2) ? hk.z : hk.w;
            float4 ww = W4[(k4 * 4 + i) * 16 + jq];
            acc.x += hsc * ww.x; acc.y += hsc * ww.y; acc.z += hsc * ww.z; acc.w += hsc * ww.w;
        }
    }
    acc.x = fmaxf(acc.x, 0.f); acc.y = fmaxf(acc.y, 0.f);
    acc.z = fmaxf(acc.z, 0.f); acc.w = fmaxf(acc.w, 0.f);
    float4 g4 = ((const float4*)gam)[jq];
    float4 b4 = ((const float4*)bet)[jq];
    float4 mm4 = ((const float4*)rmean)[jq];
    float4 v4 = ((const float4*)rvar)[jq];
    float4 hres = ((const float4*)hin)[tid];
    float4 y;
    y.x = g4.x * (acc.x - mm4.x) * rsqrtf(v4.x + BN_EPS) + b4.x + hres.x;
    y.y = g4.y * (acc.y - mm4.y) * rsqrtf(v4.y + BN_EPS) + b4.y + hres.y;
    y.z = g4.z * (acc.z - mm4.z) * rsqrtf(v4.z + BN_EPS) + b4.z + hres.z;
    y.w = g4.w * (acc.w - mm4.w) * rsqrtf(v4.w + BN_EPS) + b4.w + hres.w;
    ((float4*)hout)[tid] = y;
}

__global__ __launch_bounds__(256) void k_pool_head(
    const float* __restrict__ h, const int* __restrict__ start,
    const float* __restrict__ W1, const float* __restrict__ b1,
    const float* __restrict__ W2, const float* __restrict__ b2,
    float* __restrict__ out)
{
    __shared__ float sums[16][68];
    __shared__ float pl[HDIM];
    __shared__ float zl[HDIM];
    int g = blockIdx.x;
    int s0 = start[g], s1 = start[g + 1];
    int t = threadIdx.x, jq = t & 15, rp = t >> 4;
    float4 acc = make_float4(0.f, 0.f, 0.f, 0.f);
    for (int n = s0 + rp; n < s1; n += 16) {
        float4 v = ((const float4*)h)[(size_t)n * 16 + jq];
        acc.x += v.x; acc.y += v.y; acc.z += v.z; acc.w += v.w;
    }
    *(float4*)&sums[rp][jq * 4] = acc;
    __syncthreads();
    if (t < HDIM) {
        float a = 0.f;
        #pragma unroll
        for (int r = 0; r < 16; ++r) a += sums[r][t];
        pl[t] = a / fmaxf((float)(s1 - s0), 1.0f);
    }
    __syncthreads();
    if (t < HDIM) {
        float a = b1[t];
        #pragma unroll
        for (int k = 0; k < HDIM; ++k) a += pl[k] * W1[k * HDIM + t];
        zl[t] = fmaxf(a, 0.f);
    }
    __syncthreads();
    if (t < OUT_DIM) {
        float a = b2[t];
        #pragma unroll
        for (int k = 0; k < HDIM; ++k) a += zl[k] * W2[k * OUT_DIM + t];
        out[(size_t)g * OUT_DIM + t] = a;
    }
}

// ============ launch ============
extern "C" void kernel_launch(void* const* d_in, const int* in_sizes, int n_in,
                              void* d_out, int out_size, void* d_ws, size_t ws_size,
                              hipStream_t stream) {
    const float* x     = (const float*)d_in[0];
    const float* eattr = (const float*)d_in[1];
    const int*   src   = (const int*)d_in[2];
    const int*   dst   = (const int*)d_in[3];
    const int*   batch = (const int*)d_in[4];
    const float* Wx    = (const float*)d_in[5];
    const float* bx    = (const float*)d_in[6];
    const float* We    = (const float*)d_in[7];
    const float* be    = (const float*)d_in[8];
    const float* Wroot = (const float*)d_in[9];
    const float* broot = (const float*)d_in[10];
    const float* gam   = (const float*)d_in[11];
    const float* bet   = (const float*)d_in[12];
    const float* rmean = (const float*)d_in[13];
    const float* rvar  = (const float*)d_in[14];
    const float* W1    = (const float*)d_in[15];
    const float* b1    = (const float*)d_in[16];
    const float* W2    = (const float*)d_in[17];
    const float* b2    = (const float*)d_in[18];
    float* out = (float*)d_out;

    const int N = in_sizes[0] / IN_DIM;
    const int E = in_sizes[2];
    const int G = out_size / OUT_DIM;

    char* ws = (char*)d_ws;
    size_t off = 0;
    auto alloc = [&](size_t bytes) -> void* {
        void* p = ws + off;
        off = (off + bytes + 255) & ~(size_t)255;
        return p;
    };
    float*    h0    = (float*)alloc((size_t)N * HDIM * 4);
    float*    h1    = (float*)alloc((size_t)N * HDIM * 4);
    _Float16* eaH   = (_Float16*)alloc((size_t)E * 16 * 2);
    uint4*    WeB   = (uint4*)alloc((size_t)3 * 128 * 64 * 16);
    int*      start = (int*)alloc((size_t)(G + 1) * 4);
    float*    agg   = (float*)alloc((size_t)N * HDIM * 4);
    int*      degI  = (int*)alloc((size_t)((N + 3) & ~3) * 4);
    (void)ws_size; (void)n_in;

    FusedParams p;
    p.x = x; p.ea = eattr; p.We = We; p.be = be; p.Wx = Wx; p.bx = bx;
    p.Wroot = Wroot; p.broot = broot; p.gam = gam; p.bet = bet;
    p.rmean = rmean; p.rvar = rvar; p.W1 = W1; p.b1 = b1; p.W2 = W2; p.b2 = b2;
    p.src = src; p.dst = dst; p.batch = batch;
    p.out = out; p.h0 = h0; p.h1 = h1; p.agg = agg;
    p.eaH = eaH; p.WeB = WeB; p.degI = degI; p.start = start;
    p.N = N; p.E = E; p.G = G;

    int maxb = 0;
    hipError_t qerr = hipOccupancyMaxActiveBlocksPerMultiprocessor(&maxb, k_fused, 256, 0);
    int grid = 1024;
    if (qerr == hipSuccess && maxb > 0) {
        int cap = maxb * 256;               // 256 CUs on MI355X
        if (cap < grid) grid = cap;
    }
    if (grid < 1) grid = 256;

    void* args[] = { &p };
    hipError_t err = hipLaunchCooperativeKernel((const void*)k_fused, dim3(grid), dim3(256),
                                                args, 0, stream);
    if (err != hipSuccess) {
        // -------- fallback: non-cooperative sequence --------
        const int n16 = ((N + 3) & ~3) / 4;
        const int aggN16 = N * 16;
        k_zero<<<(aggN16 + 255) / 256, 256, 0, stream>>>((uint4*)agg, aggN16);
        k_zero<<<(n16 + 255) / 256, 256, 0, stream>>>((uint4*)degI, n16);
        const int PACKB = 96;
        const int ENCB  = (N * 16 + 255) / 256;
        const int PREPB = (E * 8 + 255) / 256;
        k_setup<<<PACKB + ENCB + PREPB + 1, 256, 0, stream>>>(
            We, WeB, x, Wx, bx, h0, eattr, eaH, dst, degI, batch, start,
            N, E, G, PACKB, ENCB, PREPB);
        const float* hin = h0;
        float* hout = h1;
        const int edgeBlocks = (E + 63) / 64;
        for (int l = 0; l < 3; ++l) {
            k_edge_fb<<<edgeBlocks, 256, 0, stream>>>(
                (const uint4*)eaH, WeB + (size_t)l * 8192, be + (size_t)l * 4096,
                hin, src, dst, agg, E);
            k_update_fb<<<(N * 16 + 255) / 256, 256, 0, stream>>>(
                agg, degI, hin, Wroot + (size_t)l * 4096, broot + (size_t)l * 64,
                gam + (size_t)l * 64, bet + (size_t)l * 64, rmean + (size_t)l * 64,
                rvar + (size_t)l * 64, hout, N);
            float* tmp = hout; hout = (float*)hin; hin = tmp;
        }
        k_pool_head<<<G, 256, 0, stream>>>(hin, start, W1, b1, W2, b2, out);
    }
}

// Round 9
// 211.939 us; speedup vs baseline: 3.6147x; 3.6147x over previous
//
#include <hip/hip_runtime.h>
#include <hip/hip_bf16.h>

typedef _Float16 f16x2 __attribute__((ext_vector_type(2)));
typedef _Float16 f16x8 __attribute__((ext_vector_type(8)));
typedef float    f32x16 __attribute__((ext_vector_type(16)));

#define IN_DIM   32
#define EDGE_DIM 16
#define HDIM     64
#define OUT_DIM  6
#define BN_EPS   1e-5f

// ============ zero agg+degI (one contiguous region, one dispatch) ============
__global__ void k_zero(uint4* __restrict__ p, int n16) {
    int i = blockIdx.x * 256 + threadIdx.x;
    if (i < n16) p[i] = make_uint4(0u, 0u, 0u, 0u);
}

// ============ fused setup: pack We (32x32 B-frags) | encode h0 | prep eaH+deg | bounds ============
__global__ __launch_bounds__(256) void k_setup(
    const float* __restrict__ We, uint4* __restrict__ WeB,
    const float* __restrict__ x, const float* __restrict__ Wx,
    const float* __restrict__ bx, float* __restrict__ h,
    const float* __restrict__ ea, _Float16* __restrict__ eaH,
    const int* __restrict__ dstI, int* __restrict__ degI,
    const int* __restrict__ batch, int* __restrict__ start,
    int N, int E, int G, int PACKB, int ENCB, int PREPB)
{
    int bid = blockIdx.x;
    int t = threadIdx.x;
    if (bid < PACKB) {                 // pack: WeB[layer][h*2+oh][lane] f16x8
        int tid = bid * 256 + t;       // lane: col=oh*32+(lane&31), k=8*(lane>>5)+j
        int tile = tid >> 6, lane = tid & 63;
        int layer = tile >> 7;
        int r = tile & 127;
        int hh = r >> 1, oh = r & 1;
        int col = hh * 64 + oh * 32 + (lane & 31);
        int kbase = 8 * (lane >> 5);
        const float* base = We + (size_t)layer * 65536 + col;
        f16x8 v;
        #pragma unroll
        for (int j = 0; j < 8; ++j) v[j] = (_Float16)base[(size_t)(kbase + j) * 4096];
        WeB[(size_t)tile * 64 + lane] = __builtin_bit_cast(uint4, v);
        return;
    }
    bid -= PACKB;
    if (bid < ENCB) {                  // encode: h0 = x @ Wx + bx
        int tid = bid * 256 + t;
        int n = tid >> 4, jq = tid & 15;
        if (n >= N) return;
        const float4* W4 = (const float4*)Wx;
        float4 acc = ((const float4*)bx)[jq];
        const float4* xv = (const float4*)(x + (size_t)n * IN_DIM);
        #pragma unroll
        for (int k4 = 0; k4 < 8; ++k4) {
            float4 xk = xv[k4];
            #pragma unroll
            for (int i = 0; i < 4; ++i) {
                float xs = (i == 0) ? xk.x : (i == 1) ? xk.y : (i == 2) ? xk.z : xk.w;
                float4 ww = W4[(k4 * 4 + i) * 16 + jq];
                acc.x += xs * ww.x; acc.y += xs * ww.y; acc.z += xs * ww.z; acc.w += xs * ww.w;
            }
        }
        ((float4*)h)[tid] = acc;
        return;
    }
    bid -= ENCB;
    if (bid < PREPB) {                 // prep: eaH f16 convert + degree count
        int tid = bid * 256 + t;
        int E8 = E * 8;
        if (tid < E8) {
            float2 v = ((const float2*)ea)[tid];
            f16x2 r; r[0] = (_Float16)v.x; r[1] = (_Float16)v.y;
            ((f16x2*)eaH)[tid] = r;
        }
        if (tid < E) atomicAdd(&degI[dstI[tid]], 1);
        return;
    }
    if (t <= G) {                      // bounds (batch sorted)
        int lo = 0, hi = N;
        while (lo < hi) { int mid = (lo + hi) >> 1; if (batch[mid] < t) lo = mid + 1; else hi = mid; }
        start[t] = lo;
    }
}

// ============ fused edge MLP (32x32x16 MFMA, K=16 exact) + relu*hs reduce + atomic scatter ============
// Block: 64 edges, 4 waves = (edge-half gp) x (o-half oh). One f32 atomic per (e,o).
__global__ __launch_bounds__(256, 4) void k_edge(
    const uint4* __restrict__ eaH4, const uint4* __restrict__ WeB,
    const float* __restrict__ be, const float* __restrict__ hin,
    const int* __restrict__ srcI, const int* __restrict__ dstI,
    float* __restrict__ agg, int E)
{
    __shared__ __align__(16) float hsT[64][68];
    __shared__ float beL[4096];
    const int t = threadIdx.x;
    const int l = t & 63;
    const int w = t >> 6;
    const int eb = blockIdx.x * 64;
    {
        const float4* bg = (const float4*)be;
        float4* bs = (float4*)beL;
        for (int i = t; i < 1024; i += 256) bs[i] = bg[i];
    }
    {
        int egc = min(eb + l, E - 1);
        int s = srcI[egc];
        const float4* hp = (const float4*)(hin + (size_t)s * HDIM + w * 16);
        float4 a = hp[0], b = hp[1], c = hp[2], d = hp[3];
        hsT[w*16+ 0][l] = a.x; hsT[w*16+ 1][l] = a.y; hsT[w*16+ 2][l] = a.z; hsT[w*16+ 3][l] = a.w;
        hsT[w*16+ 4][l] = b.x; hsT[w*16+ 5][l] = b.y; hsT[w*16+ 6][l] = b.z; hsT[w*16+ 7][l] = b.w;
        hsT[w*16+ 8][l] = c.x; hsT[w*16+ 9][l] = c.y; hsT[w*16+10][l] = c.z; hsT[w*16+11][l] = c.w;
        hsT[w*16+12][l] = d.x; hsT[w*16+13][l] = d.y; hsT[w*16+14][l] = d.z; hsT[w*16+15][l] = d.w;
    }
    __syncthreads();
    const int gp = w >> 1, oh = w & 1;
    const int ebw = eb + gp * 32, elw = gp * 32;
    const int row = l & 31, kg = l >> 5, obase = oh * 32;
    int ea_e = min(ebw + row, E - 1);
    f16x8 A = __builtin_bit_cast(f16x8, eaH4[(size_t)ea_e * 2 + kg]);
    float m[16];
    #pragma unroll
    for (int j = 0; j < 16; ++j) m[j] = 0.f;
    const uint4* Bb = WeB + (size_t)oh * 64 + l;
    uint4 Bv = Bb[0];
    for (int hh = 0; hh < 64; ++hh) {
        uint4 Bn;
        if (hh < 63) Bn = Bb[(size_t)(hh + 1) * 128];
        float bias = beL[hh * 64 + obase + row];
        f32x16 cin;
        #pragma unroll
        for (int j = 0; j < 16; ++j) cin[j] = bias;
        f32x16 z = __builtin_amdgcn_mfma_f32_32x32x16_f16(A, __builtin_bit_cast(f16x8, Bv), cin, 0, 0, 0);
        float4 q0 = *(const float4*)&hsT[hh][elw + 4 * kg + 0];
        float4 q1 = *(const float4*)&hsT[hh][elw + 4 * kg + 8];
        float4 q2 = *(const float4*)&hsT[hh][elw + 4 * kg + 16];
        float4 q3 = *(const float4*)&hsT[hh][elw + 4 * kg + 24];
        m[0]+=fmaxf(z[0],0.f)*q0.x;  m[1]+=fmaxf(z[1],0.f)*q0.y;
        m[2]+=fmaxf(z[2],0.f)*q0.z;  m[3]+=fmaxf(z[3],0.f)*q0.w;
        m[4]+=fmaxf(z[4],0.f)*q1.x;  m[5]+=fmaxf(z[5],0.f)*q1.y;
        m[6]+=fmaxf(z[6],0.f)*q1.z;  m[7]+=fmaxf(z[7],0.f)*q1.w;
        m[8]+=fmaxf(z[8],0.f)*q2.x;  m[9]+=fmaxf(z[9],0.f)*q2.y;
        m[10]+=fmaxf(z[10],0.f)*q2.z; m[11]+=fmaxf(z[11],0.f)*q2.w;
        m[12]+=fmaxf(z[12],0.f)*q3.x; m[13]+=fmaxf(z[13],0.f)*q3.y;
        m[14]+=fmaxf(z[14],0.f)*q3.z; m[15]+=fmaxf(z[15],0.f)*q3.w;
        Bv = Bn;
    }
    #pragma unroll
    for (int j = 0; j < 16; ++j) {
        int e = ebw + (j & 3) + 8 * (j >> 2) + 4 * kg;
        if (e < E) atomicAdd(&agg[(size_t)dstI[e] * HDIM + obase + row], m[j]);
    }
}

// ============ node update: mean, root GEMV, relu, BN(eval), residual; self-zeroes agg ============
__global__ void k_update(
    float* __restrict__ agg, const int* __restrict__ degI,
    const float* __restrict__ hin, const float* __restrict__ Wroot,
    const float* __restrict__ broot, const float* __restrict__ gam,
    const float* __restrict__ bet, const float* __restrict__ rmean,
    const float* __restrict__ rvar, float* __restrict__ hout, int N)
{
    int tid = blockIdx.x * 256 + threadIdx.x;
    int n = tid >> 4, jq = tid & 15;
    if (n >= N) return;
    float dinv = 1.0f / fmaxf((float)degI[n], 1.0f);
    float4 acc = ((const float4*)broot)[jq];
    float4 ag = ((const float4*)agg)[tid];
    ((float4*)agg)[tid] = make_float4(0.f, 0.f, 0.f, 0.f);
    acc.x += ag.x * dinv; acc.y += ag.y * dinv; acc.z += ag.z * dinv; acc.w += ag.w * dinv;
    const float4* W4 = (const float4*)Wroot;
    const float4* hv = (const float4*)(hin + (size_t)n * HDIM);
    #pragma unroll
    for (int k4 = 0; k4 < 16; ++k4) {
        float4 hk = hv[k4];
        #pragma unroll
        for (int i = 0; i < 4; ++i) {
            float hsc = (i == 0) ? hk.x : (i == 1) ? hk.y : (i == 2) ? hk.z : hk.w;
            float4 ww = W4[(k4 * 4 + i) * 16 + jq];
            acc.x += hsc * ww.x; acc.y += hsc * ww.y; acc.z += hsc * ww.z; acc.w += hsc * ww.w;
        }
    }
    acc.x = fmaxf(acc.x, 0.f); acc.y = fmaxf(acc.y, 0.f);
    acc.z = fmaxf(acc.z, 0.f); acc.w = fmaxf(acc.w, 0.f);
    float4 g4 = ((const float4*)gam)[jq];
    float4 b4 = ((const float4*)bet)[jq];
    float4 mm4 = ((const float4*)rmean)[jq];
    float4 v4 = ((const float4*)rvar)[jq];
    float4 hres = ((const float4*)hin)[tid];
    float4 y;
    y.x = g4.x * (acc.x - mm4.x) * rsqrtf(v4.x + BN_EPS) + b4.x + hres.x;
    y.y = g4.y * (acc.y - mm4.y) * rsqrtf(v4.y + BN_EPS) + b4.y + hres.y;
    y.z = g4.z * (acc.z - mm4.z) * rsqrtf(v4.z + BN_EPS) + b4.z + hres.z;
    y.w = g4.w * (acc.w - mm4.w) * rsqrtf(v4.w + BN_EPS) + b4.w + hres.w;
    ((float4*)hout)[tid] = y;
}

// ============ fused pool (segment mean) + MLP head; no atomics ============
__global__ __launch_bounds__(256) void k_pool_head(
    const float* __restrict__ h, const int* __restrict__ start,
    const float* __restrict__ W1, const float* __restrict__ b1,
    const float* __restrict__ W2, const float* __restrict__ b2,
    float* __restrict__ out)
{
    __shared__ float sums[16][68];
    __shared__ float pl[HDIM];
    __shared__ float zl[HDIM];
    int g = blockIdx.x;
    int s0 = start[g], s1 = start[g + 1];
    int t = threadIdx.x, jq = t & 15, rp = t >> 4;
    float4 acc = make_float4(0.f, 0.f, 0.f, 0.f);
    for (int n = s0 + rp; n < s1; n += 16) {
        float4 v = ((const float4*)h)[(size_t)n * 16 + jq];
        acc.x += v.x; acc.y += v.y; acc.z += v.z; acc.w += v.w;
    }
    *(float4*)&sums[rp][jq * 4] = acc;
    __syncthreads();
    if (t < HDIM) {
        float a = 0.f;
        #pragma unroll
        for (int r = 0; r < 16; ++r) a += sums[r][t];
        pl[t] = a / fmaxf((float)(s1 - s0), 1.0f);
    }
    __syncthreads();
    if (t < HDIM) {
        float a = b1[t];
        #pragma unroll
        for (int k = 0; k < HDIM; ++k) a += pl[k] * W1[k * HDIM + t];
        zl[t] = fmaxf(a, 0.f);
    }
    __syncthreads();
    if (t < OUT_DIM) {
        float a = b2[t];
        #pragma unroll
        for (int k = 0; k < HDIM; ++k) a += zl[k] * W2[k * OUT_DIM + t];
        out[(size_t)g * OUT_DIM + t] = a;
    }
}

// ============ launch: 9 dispatches, no cooperative sync ============
extern "C" void kernel_launch(void* const* d_in, const int* in_sizes, int n_in,
                              void* d_out, int out_size, void* d_ws, size_t ws_size,
                              hipStream_t stream) {
    const float* x     = (const float*)d_in[0];
    const float* eattr = (const float*)d_in[1];
    const int*   src   = (const int*)d_in[2];
    const int*   dst   = (const int*)d_in[3];
    const int*   batch = (const int*)d_in[4];
    const float* Wx    = (const float*)d_in[5];
    const float* bx    = (const float*)d_in[6];
    const float* We    = (const float*)d_in[7];
    const float* be    = (const float*)d_in[8];
    const float* Wroot = (const float*)d_in[9];
    const float* broot = (const float*)d_in[10];
    const float* gam   = (const float*)d_in[11];
    const float* bet   = (const float*)d_in[12];
    const float* rmean = (const float*)d_in[13];
    const float* rvar  = (const float*)d_in[14];
    const float* W1    = (const float*)d_in[15];
    const float* b1    = (const float*)d_in[16];
    const float* W2    = (const float*)d_in[17];
    const float* b2    = (const float*)d_in[18];
    float* out = (float*)d_out;

    const int N = in_sizes[0] / IN_DIM;
    const int E = in_sizes[2];
    const int G = out_size / OUT_DIM;

    char* ws = (char*)d_ws;
    size_t off = 0;
    auto alloc = [&](size_t bytes) -> void* {
        void* p = ws + off;
        off = (off + bytes + 255) & ~(size_t)255;
        return p;
    };
    float*    h0    = (float*)alloc((size_t)N * HDIM * 4);
    float*    h1    = (float*)alloc((size_t)N * HDIM * 4);
    _Float16* eaH   = (_Float16*)alloc((size_t)E * 16 * 2);
    uint4*    WeB   = (uint4*)alloc((size_t)3 * 128 * 64 * 16);
    int*      start = (int*)alloc((size_t)(G + 1) * 4);
    // contiguous zero region: agg + degI
    size_t zoff = off;
    float*    agg   = (float*)alloc((size_t)N * HDIM * 4);
    int*      degI  = (int*)alloc((size_t)N * 4);
    size_t zbytes = off - zoff;                 // 256-padded -> 16-divisible
    (void)ws_size; (void)n_in;

    const int n16 = (int)(zbytes / 16);
    k_zero<<<(n16 + 255) / 256, 256, 0, stream>>>((uint4*)agg, n16);

    const int PACKB = 96;
    const int ENCB  = (N * 16 + 255) / 256;
    const int PREPB = (E * 8 + 255) / 256;
    k_setup<<<PACKB + ENCB + PREPB + 1, 256, 0, stream>>>(
        We, WeB, x, Wx, bx, h0, eattr, eaH, dst, degI, batch, start,
        N, E, G, PACKB, ENCB, PREPB);

    const float* hin = h0;
    float* hout = h1;
    const int edgeBlocks = (E + 63) / 64;
    for (int l = 0; l < 3; ++l) {
        k_edge<<<edgeBlocks, 256, 0, stream>>>(
            (const uint4*)eaH, WeB + (size_t)l * 8192, be + (size_t)l * 4096,
            hin, src, dst, agg, E);
        k_update<<<(N * 16 + 255) / 256, 256, 0, stream>>>(
            agg, degI, hin, Wroot + (size_t)l * 4096, broot + (size_t)l * 64,
            gam + (size_t)l * 64, bet + (size_t)l * 64, rmean + (size_t)l * 64,
            rvar + (size_t)l * 64, hout, N);
        float* tmp = hout; hout = (float*)hin; hin = tmp;
    }
    k_pool_head<<<G, 256, 0, stream>>>(hin, start, W1, b1, W2, b2, out);
}

// Round 10
// 198.144 us; speedup vs baseline: 3.8664x; 1.0696x over previous
//
#include <hip/hip_runtime.h>
#include <hip/hip_bf16.h>

typedef _Float16 f16x2 __attribute__((ext_vector_type(2)));
typedef _Float16 f16x8 __attribute__((ext_vector_type(8)));
typedef float    f32x16 __attribute__((ext_vector_type(16)));

#define IN_DIM   32
#define EDGE_DIM 16
#define HDIM     64
#define OUT_DIM  6
#define BN_EPS   1e-5f

// ============ zero agg+degI (one contiguous region, one dispatch) ============
__global__ void k_zero(uint4* __restrict__ p, int n16) {
    int i = blockIdx.x * 256 + threadIdx.x;
    if (i < n16) p[i] = make_uint4(0u, 0u, 0u, 0u);
}

// ============ fused setup: pack We (32x32 B-frags) | encode h0 | prep eaH+deg | bounds ============
__global__ __launch_bounds__(256) void k_setup(
    const float* __restrict__ We, uint4* __restrict__ WeB,
    const float* __restrict__ x, const float* __restrict__ Wx,
    const float* __restrict__ bx, float* __restrict__ h,
    const float* __restrict__ ea, _Float16* __restrict__ eaH,
    const int* __restrict__ dstI, int* __restrict__ degI,
    const int* __restrict__ batch, int* __restrict__ start,
    int N, int E, int G, int PACKB, int ENCB, int PREPB)
{
    int bid = blockIdx.x;
    int t = threadIdx.x;
    if (bid < PACKB) {                 // pack: WeB[layer][h*2+oh][lane] f16x8
        int tid = bid * 256 + t;       // lane: col=oh*32+(lane&31), k=8*(lane>>5)+j
        int tile = tid >> 6, lane = tid & 63;
        int layer = tile >> 7;
        int r = tile & 127;
        int hh = r >> 1, oh = r & 1;
        int col = hh * 64 + oh * 32 + (lane & 31);
        int kbase = 8 * (lane >> 5);
        const float* base = We + (size_t)layer * 65536 + col;
        f16x8 v;
        #pragma unroll
        for (int j = 0; j < 8; ++j) v[j] = (_Float16)base[(size_t)(kbase + j) * 4096];
        WeB[(size_t)tile * 64 + lane] = __builtin_bit_cast(uint4, v);
        return;
    }
    bid -= PACKB;
    if (bid < ENCB) {                  // encode: h0 = x @ Wx + bx
        int tid = bid * 256 + t;
        int n = tid >> 4, jq = tid & 15;
        if (n >= N) return;
        const float4* W4 = (const float4*)Wx;
        float4 acc = ((const float4*)bx)[jq];
        const float4* xv = (const float4*)(x + (size_t)n * IN_DIM);
        #pragma unroll
        for (int k4 = 0; k4 < 8; ++k4) {
            float4 xk = xv[k4];
            #pragma unroll
            for (int i = 0; i < 4; ++i) {
                float xs = (i == 0) ? xk.x : (i == 1) ? xk.y : (i == 2) ? xk.z : xk.w;
                float4 ww = W4[(k4 * 4 + i) * 16 + jq];
                acc.x += xs * ww.x; acc.y += xs * ww.y; acc.z += xs * ww.z; acc.w += xs * ww.w;
            }
        }
        ((float4*)h)[tid] = acc;
        return;
    }
    bid -= ENCB;
    if (bid < PREPB) {                 // prep: eaH f16 convert + degree count
        int tid = bid * 256 + t;
        int E8 = E * 8;
        if (tid < E8) {
            float2 v = ((const float2*)ea)[tid];
            f16x2 r; r[0] = (_Float16)v.x; r[1] = (_Float16)v.y;
            ((f16x2*)eaH)[tid] = r;
        }
        if (tid < E) atomicAdd(&degI[dstI[tid]], 1);
        return;
    }
    if (t <= G) {                      // bounds (batch sorted)
        int lo = 0, hi = N;
        while (lo < hi) { int mid = (lo + hi) >> 1; if (batch[mid] < t) lo = mid + 1; else hi = mid; }
        start[t] = lo;
    }
}

// ============ fused edge MLP (32x32x16 MFMA, K=16 exact) + relu*hs reduce + atomic scatter ============
// Block: 64 edges, 4 waves = (edge-half gp) x (o-half oh). One f32 atomic per (e,o).
// 4-deep register B-prefetch: named regs, h-loop unrolled x4 (covers ~440cyc > L2 latency).
__global__ __launch_bounds__(256, 4) void k_edge(
    const uint4* __restrict__ eaH4, const uint4* __restrict__ WeB,
    const float* __restrict__ be, const float* __restrict__ hin,
    const int* __restrict__ srcI, const int* __restrict__ dstI,
    float* __restrict__ agg, int E)
{
    __shared__ __align__(16) float hsT[64][68];
    __shared__ float beL[4096];
    const int t = threadIdx.x;
    const int l = t & 63;
    const int w = t >> 6;
    const int eb = blockIdx.x * 64;
    {
        const float4* bg = (const float4*)be;
        float4* bs = (float4*)beL;
        for (int i = t; i < 1024; i += 256) bs[i] = bg[i];
    }
    {
        int egc = min(eb + l, E - 1);
        int s = srcI[egc];
        const float4* hp = (const float4*)(hin + (size_t)s * HDIM + w * 16);
        float4 a = hp[0], b = hp[1], c = hp[2], d = hp[3];
        hsT[w*16+ 0][l] = a.x; hsT[w*16+ 1][l] = a.y; hsT[w*16+ 2][l] = a.z; hsT[w*16+ 3][l] = a.w;
        hsT[w*16+ 4][l] = b.x; hsT[w*16+ 5][l] = b.y; hsT[w*16+ 6][l] = b.z; hsT[w*16+ 7][l] = b.w;
        hsT[w*16+ 8][l] = c.x; hsT[w*16+ 9][l] = c.y; hsT[w*16+10][l] = c.z; hsT[w*16+11][l] = c.w;
        hsT[w*16+12][l] = d.x; hsT[w*16+13][l] = d.y; hsT[w*16+14][l] = d.z; hsT[w*16+15][l] = d.w;
    }
    __syncthreads();
    const int gp = w >> 1, oh = w & 1;
    const int ebw = eb + gp * 32, elw = gp * 32;
    const int row = l & 31, kg = l >> 5, obase = oh * 32;
    int ea_e = min(ebw + row, E - 1);
    f16x8 A = __builtin_bit_cast(f16x8, eaH4[(size_t)ea_e * 2 + kg]);
    float m[16];
    #pragma unroll
    for (int j = 0; j < 16; ++j) m[j] = 0.f;

    const uint4* Bb = WeB + (size_t)oh * 64 + l;   // stride per h: 128 uint4

    auto step = [&](const uint4& Bv, int hh) {
        float bias = beL[hh * 64 + obase + row];
        f32x16 cin;
        #pragma unroll
        for (int j = 0; j < 16; ++j) cin[j] = bias;
        f32x16 z = __builtin_amdgcn_mfma_f32_32x32x16_f16(
            A, __builtin_bit_cast(f16x8, Bv), cin, 0, 0, 0);
        float4 q0 = *(const float4*)&hsT[hh][elw + 4 * kg + 0];
        float4 q1 = *(const float4*)&hsT[hh][elw + 4 * kg + 8];
        float4 q2 = *(const float4*)&hsT[hh][elw + 4 * kg + 16];
        float4 q3 = *(const float4*)&hsT[hh][elw + 4 * kg + 24];
        m[0]  += fmaxf(z[0],  0.f) * q0.x;
        m[1]  += fmaxf(z[1],  0.f) * q0.y;
        m[2]  += fmaxf(z[2],  0.f) * q0.z;
        m[3]  += fmaxf(z[3],  0.f) * q0.w;
        m[4]  += fmaxf(z[4],  0.f) * q1.x;
        m[5]  += fmaxf(z[5],  0.f) * q1.y;
        m[6]  += fmaxf(z[6],  0.f) * q1.z;
        m[7]  += fmaxf(z[7],  0.f) * q1.w;
        m[8]  += fmaxf(z[8],  0.f) * q2.x;
        m[9]  += fmaxf(z[9],  0.f) * q2.y;
        m[10] += fmaxf(z[10], 0.f) * q2.z;
        m[11] += fmaxf(z[11], 0.f) * q2.w;
        m[12] += fmaxf(z[12], 0.f) * q3.x;
        m[13] += fmaxf(z[13], 0.f) * q3.y;
        m[14] += fmaxf(z[14], 0.f) * q3.z;
        m[15] += fmaxf(z[15], 0.f) * q3.w;
    };

    // prologue: 4 fragments in flight
    uint4 B0 = Bb[0 * 128], B1 = Bb[1 * 128], B2 = Bb[2 * 128], B3 = Bb[3 * 128];
    #pragma unroll 1
    for (int hh = 0; hh < 64; hh += 4) {
        // issue next group's loads first (WeB is tail-padded: over-read at hh=60 is safe)
        uint4 N0 = Bb[(size_t)(hh + 4) * 128];
        uint4 N1 = Bb[(size_t)(hh + 5) * 128];
        uint4 N2 = Bb[(size_t)(hh + 6) * 128];
        uint4 N3 = Bb[(size_t)(hh + 7) * 128];
        step(B0, hh + 0);
        step(B1, hh + 1);
        step(B2, hh + 2);
        step(B3, hh + 3);
        B0 = N0; B1 = N1; B2 = N2; B3 = N3;
    }

    #pragma unroll
    for (int j = 0; j < 16; ++j) {
        int e = ebw + (j & 3) + 8 * (j >> 2) + 4 * kg;
        if (e < E) atomicAdd(&agg[(size_t)dstI[e] * HDIM + obase + row], m[j]);
    }
}

// ============ node update: mean, root GEMV, relu, BN(eval), residual; self-zeroes agg ============
__global__ void k_update(
    float* __restrict__ agg, const int* __restrict__ degI,
    const float* __restrict__ hin, const float* __restrict__ Wroot,
    const float* __restrict__ broot, const float* __restrict__ gam,
    const float* __restrict__ bet, const float* __restrict__ rmean,
    const float* __restrict__ rvar, float* __restrict__ hout, int N)
{
    int tid = blockIdx.x * 256 + threadIdx.x;
    int n = tid >> 4, jq = tid & 15;
    if (n >= N) return;
    float dinv = 1.0f / fmaxf((float)degI[n], 1.0f);
    float4 acc = ((const float4*)broot)[jq];
    float4 ag = ((const float4*)agg)[tid];
    ((float4*)agg)[tid] = make_float4(0.f, 0.f, 0.f, 0.f);
    acc.x += ag.x * dinv; acc.y += ag.y * dinv; acc.z += ag.z * dinv; acc.w += ag.w * dinv;
    const float4* W4 = (const float4*)Wroot;
    const float4* hv = (const float4*)(hin + (size_t)n * HDIM);
    #pragma unroll
    for (int k4 = 0; k4 < 16; ++k4) {
        float4 hk = hv[k4];
        #pragma unroll
        for (int i = 0; i < 4; ++i) {
            float hsc = (i == 0) ? hk.x : (i == 1) ? hk.y : (i == 2) ? hk.z : hk.w;
            float4 ww = W4[(k4 * 4 + i) * 16 + jq];
            acc.x += hsc * ww.x; acc.y += hsc * ww.y; acc.z += hsc * ww.z; acc.w += hsc * ww.w;
        }
    }
    acc.x = fmaxf(acc.x, 0.f); acc.y = fmaxf(acc.y, 0.f);
    acc.z = fmaxf(acc.z, 0.f); acc.w = fmaxf(acc.w, 0.f);
    float4 g4 = ((const float4*)gam)[jq];
    float4 b4 = ((const float4*)bet)[jq];
    float4 mm4 = ((const float4*)rmean)[jq];
    float4 v4 = ((const float4*)rvar)[jq];
    float4 hres = ((const float4*)hin)[tid];
    float4 y;
    y.x = g4.x * (acc.x - mm4.x) * rsqrtf(v4.x + BN_EPS) + b4.x + hres.x;
    y.y = g4.y * (acc.y - mm4.y) * rsqrtf(v4.y + BN_EPS) + b4.y + hres.y;
    y.z = g4.z * (acc.z - mm4.z) * rsqrtf(v4.z + BN_EPS) + b4.z + hres.z;
    y.w = g4.w * (acc.w - mm4.w) * rsqrtf(v4.w + BN_EPS) + b4.w + hres.w;
    ((float4*)hout)[tid] = y;
}

// ============ fused pool (segment mean) + MLP head; no atomics ============
__global__ __launch_bounds__(256) void k_pool_head(
    const float* __restrict__ h, const int* __restrict__ start,
    const float* __restrict__ W1, const float* __restrict__ b1,
    const float* __restrict__ W2, const float* __restrict__ b2,
    float* __restrict__ out)
{
    __shared__ float sums[16][68];
    __shared__ float pl[HDIM];
    __shared__ float zl[HDIM];
    int g = blockIdx.x;
    int s0 = start[g], s1 = start[g + 1];
    int t = threadIdx.x, jq = t & 15, rp = t >> 4;
    float4 acc = make_float4(0.f, 0.f, 0.f, 0.f);
    for (int n = s0 + rp; n < s1; n += 16) {
        float4 v = ((const float4*)h)[(size_t)n * 16 + jq];
        acc.x += v.x; acc.y += v.y; acc.z += v.z; acc.w += v.w;
    }
    *(float4*)&sums[rp][jq * 4] = acc;
    __syncthreads();
    if (t < HDIM) {
        float a = 0.f;
        #pragma unroll
        for (int r = 0; r < 16; ++r) a += sums[r][t];
        pl[t] = a / fmaxf((float)(s1 - s0), 1.0f);
    }
    __syncthreads();
    if (t < HDIM) {
        float a = b1[t];
        #pragma unroll
        for (int k = 0; k < HDIM; ++k) a += pl[k] * W1[k * HDIM + t];
        zl[t] = fmaxf(a, 0.f);
    }
    __syncthreads();
    if (t < OUT_DIM) {
        float a = b2[t];
        #pragma unroll
        for (int k = 0; k < HDIM; ++k) a += zl[k] * W2[k * OUT_DIM + t];
        out[(size_t)g * OUT_DIM + t] = a;
    }
}

// ============ launch: 9 dispatches, no cooperative sync ============
extern "C" void kernel_launch(void* const* d_in, const int* in_sizes, int n_in,
                              void* d_out, int out_size, void* d_ws, size_t ws_size,
                              hipStream_t stream) {
    const float* x     = (const float*)d_in[0];
    const float* eattr = (const float*)d_in[1];
    const int*   src   = (const int*)d_in[2];
    const int*   dst   = (const int*)d_in[3];
    const int*   batch = (const int*)d_in[4];
    const float* Wx    = (const float*)d_in[5];
    const float* bx    = (const float*)d_in[6];
    const float* We    = (const float*)d_in[7];
    const float* be    = (const float*)d_in[8];
    const float* Wroot = (const float*)d_in[9];
    const float* broot = (const float*)d_in[10];
    const float* gam   = (const float*)d_in[11];
    const float* bet   = (const float*)d_in[12];
    const float* rmean = (const float*)d_in[13];
    const float* rvar  = (const float*)d_in[14];
    const float* W1    = (const float*)d_in[15];
    const float* b1    = (const float*)d_in[16];
    const float* W2    = (const float*)d_in[17];
    const float* b2    = (const float*)d_in[18];
    float* out = (float*)d_out;

    const int N = in_sizes[0] / IN_DIM;
    const int E = in_sizes[2];
    const int G = out_size / OUT_DIM;

    char* ws = (char*)d_ws;
    size_t off = 0;
    auto alloc = [&](size_t bytes) -> void* {
        void* p = ws + off;
        off = (off + bytes + 255) & ~(size_t)255;
        return p;
    };
    float*    h0    = (float*)alloc((size_t)N * HDIM * 4);
    float*    h1    = (float*)alloc((size_t)N * HDIM * 4);
    _Float16* eaH   = (_Float16*)alloc((size_t)E * 16 * 2);
    uint4*    WeB   = (uint4*)alloc((size_t)3 * 128 * 64 * 16 + 16384);  // +16KB tail pad for deep prefetch over-read
    int*      start = (int*)alloc((size_t)(G + 1) * 4);
    // contiguous zero region: agg + degI
    size_t zoff = off;
    float*    agg   = (float*)alloc((size_t)N * HDIM * 4);
    int*      degI  = (int*)alloc((size_t)N * 4);
    size_t zbytes = off - zoff;                 // 256-padded -> 16-divisible
    (void)ws_size; (void)n_in;

    const int n16 = (int)(zbytes / 16);
    k_zero<<<(n16 + 255) / 256, 256, 0, stream>>>((uint4*)agg, n16);

    const int PACKB = 96;
    const int ENCB  = (N * 16 + 255) / 256;
    const int PREPB = (E * 8 + 255) / 256;
    k_setup<<<PACKB + ENCB + PREPB + 1, 256, 0, stream>>>(
        We, WeB, x, Wx, bx, h0, eattr, eaH, dst, degI, batch, start,
        N, E, G, PACKB, ENCB, PREPB);

    const float* hin = h0;
    float* hout = h1;
    const int edgeBlocks = (E + 63) / 64;
    for (int l = 0; l < 3; ++l) {
        k_edge<<<edgeBlocks, 256, 0, stream>>>(
            (const uint4*)eaH, WeB + (size_t)l * 8192, be + (size_t)l * 4096,
            hin, src, dst, agg, E);
        k_update<<<(N * 16 + 255) / 256, 256, 0, stream>>>(
            agg, degI, hin, Wroot + (size_t)l * 4096, broot + (size_t)l * 64,
            gam + (size_t)l * 64, bet + (size_t)l * 64, rmean + (size_t)l * 64,
            rvar + (size_t)l * 64, hout, N);
        float* tmp = hout; hout = (float*)hin; hin = tmp;
    }
    k_pool_head<<<G, 256, 0, stream>>>(hin, start, W1, b1, W2, b2, out);
}